// Round 6
// baseline (336.533 us; speedup 1.0000x reference)
//
#include <hip/hip_runtime.h>
#include <hip/hip_bf16.h>
#include <math.h>

#define BB  2
#define TT  2048
#define DDE 1024
#define NHH 16
#define HDD 64

typedef __bf16 bf16_t;
typedef __attribute__((ext_vector_type(8))) __bf16 bf16x8;
typedef __attribute__((ext_vector_type(4))) __bf16 bf16x4;
typedef __attribute__((ext_vector_type(4))) float  f32x4;

#define MFMA(a, b, c) __builtin_amdgcn_mfma_f32_16x16x32_bf16((a), (b), (c), 0, 0, 0)

__device__ inline unsigned short bf2us(bf16_t x) {
    union { bf16_t h; unsigned short u; } c; c.h = x; return c.u;
}

__device__ inline void gll16(const bf16_t* g, unsigned short* l) {
    __builtin_amdgcn_global_load_lds(
        (const __attribute__((address_space(1))) void*)g,
        (__attribute__((address_space(3))) void*)l, 16, 0, 0);
}

// Stage [ROWS x 64] bf16 tile (row stride gstride elems) into LDS via
// global_load_lds, chunk-swizzled: LDS elem [r][ (c ^ (r&7))*8 + j ].
template<int ROWS>
__device__ inline void stage_tile(const bf16_t* g0, size_t gstride,
                                  unsigned short* lds, int wave, int lane)
{
    const int r8 = lane >> 3;
    const int ck = (lane & 7) ^ r8;
    constexpr int RW = ROWS / 4;
    const bf16_t* g = g0 + (size_t)(wave * RW + r8) * gstride + ck * 8;
    unsigned short* l = lds + wave * RW * 64 + lane * 8;
    #pragma unroll
    for (int i = 0; i < RW / 8; ++i)
        gll16(g + (size_t)(i * 8) * gstride, l + i * 512);
}

// uniform split-s: chunk = 4 k-tiles.  72 blocks cover qt=0..15.
// qt=2g has g+1 chunks, qt=2g+1 has g+1 chunks; cum before group g = g(g+1).
__device__ inline void split_decode4(int wid, int& qt, int& ch) {
    int g = 0, loc = wid;
    while (loc >= 2 * (g + 1)) { loc -= 2 * (g + 1); ++g; }
    if (loc >= g + 1) { qt = 2*g + 1; ch = loc - (g + 1); }
    else              { qt = 2*g;     ch = loc; }
}

// ---------------------------------------------------------------------------
// fused fp32->bf16 conversion of x, w_attn, w_k2, w_proj (contiguous dst).
// ---------------------------------------------------------------------------
__global__ __launch_bounds__(256) void cvt_all(
    const float* __restrict__ x, const float* __restrict__ wa,
    const float* __restrict__ wk, const float* __restrict__ wp,
    bf16_t* __restrict__ out)
{
    const size_t NX  = (size_t)BB*TT*DDE;
    const size_t NWA = (size_t)2*DDE*DDE;
    const size_t NW  = (size_t)DDE*DDE;
    const size_t e = ((size_t)blockIdx.x * 256 + threadIdx.x) * 4;
    const float* src;
    if (e < NX)                 src = x  + e;
    else if (e < NX + NWA)      src = wa + (e - NX);
    else if (e < NX + NWA + NW) src = wk + (e - NX - NWA);
    else                        src = wp + (e - NX - NWA - NW);
    float4 v = *(const float4*)src;
    bf16x4 o;
    o[0] = (bf16_t)v.x; o[1] = (bf16_t)v.y;
    o[2] = (bf16_t)v.z; o[3] = (bf16_t)v.w;
    *(bf16x4*)(out + e) = o;
}

// ---------------------------------------------------------------------------
// Per-head 64x64 transpose: dst[bh][d][t] = src[b][t][h*64+d].
// ---------------------------------------------------------------------------
__global__ __launch_bounds__(256) void transpose_head(
    const bf16_t* __restrict__ src, bf16_t* __restrict__ dst)
{
    const int t0 = blockIdx.x * 64, h = blockIdx.y, b = blockIdx.z;
    const int tid = threadIdx.x;
    __shared__ __align__(16) bf16_t tile[64 * 64];

    #pragma unroll
    for (int it = 0; it < 2; ++it) {
        const int t = it * 32 + (tid >> 3);
        const int cw = tid & 7;
        const int slot = (cw + (t >> 3)) & 7;
        bf16x8 v = *(const bf16x8*)(src + (size_t)(b*TT + t0 + t)*DDE + h*HDD + cw*8);
        *(bf16x8*)(tile + t*64 + slot*8) = v;
    }
    __syncthreads();
    const int bh = b * NHH + h;
    #pragma unroll
    for (int it = 0; it < 2; ++it) {
        const int d = it * 32 + (tid >> 3);
        const int co = tid & 7;
        const int slot = ((d >> 3) + co) & 7;
        bf16x8 o;
        #pragma unroll
        for (int j = 0; j < 8; ++j)
            o[j] = tile[(co*8 + j)*64 + slot*8 + (d & 7)];
        *(bf16x8*)(dst + (size_t)(bh*64 + d)*TT + t0 + co*8) = o;
    }
}

// ---------------------------------------------------------------------------
// Fused normalize + E-transpose:
//   yarb[t] = bf16(yo[t]/lsum[t]);  etg[bh][d][t] = x[t][d] - n[t-1][d]
// ---------------------------------------------------------------------------
__global__ __launch_bounds__(256) void norm_build_etg(
    const float* __restrict__ yo, const float* __restrict__ ls,
    const bf16_t* __restrict__ xb, bf16_t* __restrict__ yarb,
    bf16_t* __restrict__ etg)
{
    const int t0 = blockIdx.x * 64, h = blockIdx.y, b = blockIdx.z;
    const int tid = threadIdx.x;
    const int bh = b * NHH + h;
    __shared__ __align__(16) bf16_t tile[64 * 64];

    #pragma unroll
    for (int it = 0; it < 2; ++it) {
        const int t = it * 32 + (tid >> 3);
        const int cw = tid & 7;
        const int slot = (cw + (t >> 3)) & 7;
        const int tg = t0 + t;
        const float inv = 1.f / ls[(size_t)bh*TT + tg];
        const float* yp = yo + (size_t)(b*TT + tg)*DDE + h*HDD + cw*8;
        float4 y0 = *(const float4*)yp;
        float4 y1 = *(const float4*)(yp + 4);
        bf16x8 nb;
        nb[0] = (bf16_t)(y0.x*inv); nb[1] = (bf16_t)(y0.y*inv);
        nb[2] = (bf16_t)(y0.z*inv); nb[3] = (bf16_t)(y0.w*inv);
        nb[4] = (bf16_t)(y1.x*inv); nb[5] = (bf16_t)(y1.y*inv);
        nb[6] = (bf16_t)(y1.z*inv); nb[7] = (bf16_t)(y1.w*inv);
        *(bf16x8*)(yarb + (size_t)(b*TT + tg)*DDE + h*HDD + cw*8) = nb;
        bf16x8 ev;
        if (tg == 0) {
            #pragma unroll
            for (int u = 0; u < 8; ++u) ev[u] = (bf16_t)0.f;
        } else {
            const float invp = 1.f / ls[(size_t)bh*TT + tg - 1];
            const float* ypp = yo + (size_t)(b*TT + tg - 1)*DDE + h*HDD + cw*8;
            float4 p0 = *(const float4*)ypp;
            float4 p1 = *(const float4*)(ypp + 4);
            bf16x8 xv = *(const bf16x8*)(xb + (size_t)(b*TT + tg)*DDE + h*HDD + cw*8);
            ev[0] = (bf16_t)((float)xv[0] - p0.x*invp);
            ev[1] = (bf16_t)((float)xv[1] - p0.y*invp);
            ev[2] = (bf16_t)((float)xv[2] - p0.z*invp);
            ev[3] = (bf16_t)((float)xv[3] - p0.w*invp);
            ev[4] = (bf16_t)((float)xv[4] - p1.x*invp);
            ev[5] = (bf16_t)((float)xv[5] - p1.y*invp);
            ev[6] = (bf16_t)((float)xv[6] - p1.z*invp);
            ev[7] = (bf16_t)((float)xv[7] - p1.w*invp);
        }
        *(bf16x8*)(tile + t*64 + slot*8) = ev;
    }
    __syncthreads();
    #pragma unroll
    for (int it = 0; it < 2; ++it) {
        const int d = it * 32 + (tid >> 3);
        const int co = tid & 7;
        const int slot = ((d >> 3) + co) & 7;
        bf16x8 o;
        #pragma unroll
        for (int j = 0; j < 8; ++j)
            o[j] = tile[(co*8 + j)*64 + slot*8 + (d & 7)];
        *(bf16x8*)(etg + (size_t)(bh*64 + d)*TT + t0 + co*8) = o;
    }
}

// ---------------------------------------------------------------------------
// Fused QKV GEMM, BK=64 swizzled staging.  Region by column tile:
//   [0,1024):  q -> qkb = q*0.125*log2(e) (exp2 domain), qab = leaky(q*0.125)
//   [1024,2048): k -> qkb raw
//   [2048,3072): k2 -> kcs[t+1] = sigmoid(k2*0.0025)-0.5 (shifted, row0=0)
// ---------------------------------------------------------------------------
__global__ __launch_bounds__(256) void gemm_qkk2(
    const bf16_t* __restrict__ A, const bf16_t* __restrict__ wab,
    const bf16_t* __restrict__ wkb, const float* __restrict__ b_attn,
    const float* __restrict__ b_k2, bf16_t* __restrict__ qkb,
    bf16_t* __restrict__ qab, bf16_t* __restrict__ kcs)
{
    __shared__ __align__(16) unsigned short As[128 * 64];
    __shared__ __align__(16) unsigned short Bs[128 * 64];
    const int tid  = threadIdx.x;
    const int wave = tid >> 6, lane = tid & 63;
    const int l15  = lane & 15, quad = lane >> 4;
    const int bm = blockIdx.y * 128, bn = blockIdx.x * 128;
    const int wm = (wave & 1) * 64, wn = (wave >> 1) * 64;
    const int region = bn >> 10;
    const int K = DDE;

    const bf16_t* W = (region < 2) ? wab + (size_t)bn * K
                                   : wkb + (size_t)(bn - 2048) * K;
    const float* bp = (region < 2) ? b_attn + bn : b_k2 + (bn - 2048);
    const bf16_t* Ab = A + (size_t)bm * K;

    f32x4 acc[4][4];
    #pragma unroll
    for (int i = 0; i < 4; ++i)
        #pragma unroll
        for (int j = 0; j < 4; ++j) acc[i][j] = (f32x4)0.f;

    for (int k0 = 0; k0 < K; k0 += 64) {
        __syncthreads();
        stage_tile<128>(Ab + k0, K, As, wave, lane);
        stage_tile<128>(W  + k0, K, Bs, wave, lane);
        __syncthreads();
        bf16x8 af[4][2], bfr[4][2];
        #pragma unroll
        for (int mt = 0; mt < 4; ++mt)
            #pragma unroll
            for (int kh = 0; kh < 2; ++kh)
                af[mt][kh] = *(const bf16x8*)(As + (wm + mt*16 + l15)*64
                                              + (((kh*4 + quad) ^ (l15 & 7))*8));
        #pragma unroll
        for (int nt = 0; nt < 4; ++nt)
            #pragma unroll
            for (int kh = 0; kh < 2; ++kh)
                bfr[nt][kh] = *(const bf16x8*)(Bs + (wn + nt*16 + l15)*64
                                               + (((kh*4 + quad) ^ (l15 & 7))*8));
        #pragma unroll
        for (int mt = 0; mt < 4; ++mt)
            #pragma unroll
            for (int nt = 0; nt < 4; ++nt) {
                acc[mt][nt] = MFMA(af[mt][0], bfr[nt][0], acc[mt][nt]);
                acc[mt][nt] = MFMA(af[mt][1], bfr[nt][1], acc[mt][nt]);
            }
    }

    #pragma unroll
    for (int nt = 0; nt < 4; ++nt) {
        const int cl = wn + nt*16 + l15;
        const float bj = bp[cl];
        const int cg = bn + cl;
        #pragma unroll
        for (int mt = 0; mt < 4; ++mt)
            #pragma unroll
            for (int r = 0; r < 4; ++r) {
                const int row = bm + wm + mt*16 + quad*4 + r;
                const float v = acc[mt][nt][r] + bj;
                if (region == 0) {
                    qkb[(size_t)row * (2*DDE) + cg] = (bf16_t)(v * 0.180336880f);
                    const float z = v * 0.125f;
                    qab[(size_t)row * DDE + cg] = (bf16_t)((v > 0.f) ? 0.02f*z : z);
                } else if (region == 1) {
                    qkb[(size_t)row * (2*DDE) + cg] = (bf16_t)v;
                } else {
                    const int c2 = cg - 2048;
                    const float kc = 1.f/(1.f + __expf(-v*0.0025f)) - 0.5f;
                    if (((row + 1) & (TT - 1)) != 0)
                        kcs[(size_t)(row + 1) * DDE + c2] = (bf16_t)kc;
                    if ((row & (TT - 1)) == 0)
                        kcs[(size_t)row * DDE + c2] = (bf16_t)0.f;
                }
            }
    }
}

// ---------------------------------------------------------------------------
// proj GEMM, 64x128 tile (512 blocks -> 2/CU), BK=64, fp32 out.
// ---------------------------------------------------------------------------
__global__ __launch_bounds__(256) void gemm_proj(
    const bf16_t* __restrict__ A, const bf16_t* __restrict__ W,
    const float* __restrict__ bias, float* __restrict__ C,
    int M, int N, int K, float bmul)
{
    __shared__ __align__(16) unsigned short As[64 * 64];
    __shared__ __align__(16) unsigned short Bs[128 * 64];
    const int tid  = threadIdx.x;
    const int wave = tid >> 6, lane = tid & 63;
    const int l15  = lane & 15, quad = lane >> 4;
    const int bm = blockIdx.y * 64, bn = blockIdx.x * 128;
    const int wm = (wave & 1) * 32, wn = (wave >> 1) * 64;

    const bf16_t* Ab = A + (size_t)bm * K;
    const bf16_t* Wb = W + (size_t)bn * K;

    f32x4 acc[2][4];
    #pragma unroll
    for (int i = 0; i < 2; ++i)
        #pragma unroll
        for (int j = 0; j < 4; ++j) acc[i][j] = (f32x4)0.f;

    for (int k0 = 0; k0 < K; k0 += 64) {
        __syncthreads();
        stage_tile<64>(Ab + k0, K, As, wave, lane);
        stage_tile<128>(Wb + k0, K, Bs, wave, lane);
        __syncthreads();
        bf16x8 af[2][2], bfr[4][2];
        #pragma unroll
        for (int mt = 0; mt < 2; ++mt)
            #pragma unroll
            for (int kh = 0; kh < 2; ++kh)
                af[mt][kh] = *(const bf16x8*)(As + (wm + mt*16 + l15)*64
                                              + (((kh*4 + quad) ^ (l15 & 7))*8));
        #pragma unroll
        for (int nt = 0; nt < 4; ++nt)
            #pragma unroll
            for (int kh = 0; kh < 2; ++kh)
                bfr[nt][kh] = *(const bf16x8*)(Bs + (wn + nt*16 + l15)*64
                                               + (((kh*4 + quad) ^ (l15 & 7))*8));
        #pragma unroll
        for (int mt = 0; mt < 2; ++mt)
            #pragma unroll
            for (int nt = 0; nt < 4; ++nt) {
                acc[mt][nt] = MFMA(af[mt][0], bfr[nt][0], acc[mt][nt]);
                acc[mt][nt] = MFMA(af[mt][1], bfr[nt][1], acc[mt][nt]);
            }
    }

    #pragma unroll
    for (int nt = 0; nt < 4; ++nt) {
        const int col = bn + wn + nt*16 + l15;
        const float bj = bias[col] * bmul;
        #pragma unroll
        for (int mt = 0; mt < 2; ++mt)
            #pragma unroll
            for (int r = 0; r < 4; ++r) {
                const int row = bm + wm + mt*16 + quad*4 + r;
                C[(size_t)row * N + col] = acc[mt][nt][r] + bj;
            }
    }
}

// ---------------------------------------------------------------------------
// AR: fixed-max flash attention, uniform split-s (chunk=4 tiles).
// ---------------------------------------------------------------------------
__global__ __launch_bounds__(256) void attn_ar_mfma(
    const bf16_t* __restrict__ qkb, const bf16_t* __restrict__ vtg,
    float* __restrict__ yo, float* __restrict__ lsum)
{
    int qt, ch;
    split_decode4((int)blockIdx.x, qt, ch);
    const int h = blockIdx.y, b = blockIdx.z;
    const int tid = threadIdx.x, wave = tid >> 6, lane = tid & 63;
    const int l15 = lane & 15, quad = lane >> 4;
    const int q0 = qt * 128;
    const int bh = b * NHH + h;

    __shared__ __align__(16) unsigned short Qs[128 * 64];
    __shared__ __align__(16) unsigned short Ks[64 * 64];
    __shared__ __align__(16) unsigned short Vs[64 * 64];
    __shared__ __align__(16) unsigned short Pw[4][32 * 72];

    stage_tile<128>(qkb + (size_t)(b*TT + q0) * (2*DDE) + h*HDD, 2*DDE, Qs, wave, lane);
    __syncthreads();

    bf16x8 qf[2][2];
    #pragma unroll
    for (int mt = 0; mt < 2; ++mt)
        #pragma unroll
        for (int kc = 0; kc < 2; ++kc)
            qf[mt][kc] = *(const bf16x8*)(Qs + (wave*32 + mt*16 + l15)*64
                                          + ((kc*4 + quad) ^ (l15 & 7))*8);

    f32x4 o[2][4];
    float lrow[2][4];
    #pragma unroll
    for (int mt = 0; mt < 2; ++mt) {
        #pragma unroll
        for (int nt = 0; nt < 4; ++nt) o[mt][nt] = (f32x4)0.f;
        #pragma unroll
        for (int r = 0; r < 4; ++r) lrow[mt][r] = 0.f;
    }

    const int qw0 = q0 + wave * 32;
    const int kt0 = ch * 4;
    const int kt1 = min(kt0 + 4, 2*qt + 2);
    bool did = false;

    for (int kt = kt0; kt < kt1; ++kt) {
        const int s0 = kt * 64;
        __syncthreads();
        stage_tile<64>(qkb + (size_t)(b*TT + s0)*(2*DDE) + DDE + h*HDD, 2*DDE, Ks, wave, lane);
        stage_tile<64>(vtg + (size_t)(bh*64)*TT + s0, TT, Vs, wave, lane);
        __syncthreads();
        if (s0 > qw0 + 31) continue;
        did = true;

        f32x4 sv[2][4];
        #pragma unroll
        for (int nt = 0; nt < 4; ++nt) {
            const unsigned short* kr = Ks + (nt*16 + l15)*64;
            bf16x8 kb0 = *(const bf16x8*)(kr + ((quad    ) ^ (l15 & 7))*8);
            bf16x8 kb1 = *(const bf16x8*)(kr + ((quad + 4) ^ (l15 & 7))*8);
            #pragma unroll
            for (int mt = 0; mt < 2; ++mt) {
                f32x4 z = (f32x4)0.f;
                z = MFMA(qf[mt][0], kb0, z);
                z = MFMA(qf[mt][1], kb1, z);
                sv[mt][nt] = z;
            }
        }
        const bool domask = (s0 + 63 > qw0);
        unsigned short* pw = Pw[wave];
        #pragma unroll
        for (int mt = 0; mt < 2; ++mt)
            #pragma unroll
            for (int r = 0; r < 4; ++r)
                #pragma unroll
                for (int nt = 0; nt < 4; ++nt) {
                    float p = exp2f(sv[mt][nt][r]);
                    if (domask) {
                        const int qg = qw0 + mt*16 + quad*4 + r;
                        const int sg = s0 + nt*16 + l15;
                        if (sg > qg) p = 0.f;
                    }
                    lrow[mt][r] += p;
                    pw[(mt*16 + quad*4 + r)*72 + nt*16 + l15] = bf2us((bf16_t)p);
                }
        bf16x8 pa[2][2];
        #pragma unroll
        for (int mt = 0; mt < 2; ++mt)
            #pragma unroll
            for (int sc = 0; sc < 2; ++sc)
                pa[mt][sc] = *(const bf16x8*)(pw + (mt*16 + l15)*72 + sc*32 + quad*8);
        #pragma unroll
        for (int nt = 0; nt < 4; ++nt) {
            const unsigned short* vr = Vs + (nt*16 + l15)*64;
            bf16x8 vb0 = *(const bf16x8*)(vr + ((quad    ) ^ (l15 & 7))*8);
            bf16x8 vb1 = *(const bf16x8*)(vr + ((quad + 4) ^ (l15 & 7))*8);
            #pragma unroll
            for (int mt = 0; mt < 2; ++mt) {
                o[mt][nt] = MFMA(pa[mt][0], vb0, o[mt][nt]);
                o[mt][nt] = MFMA(pa[mt][1], vb1, o[mt][nt]);
            }
        }
    }

    if (did) {
        #pragma unroll
        for (int mt = 0; mt < 2; ++mt)
            #pragma unroll
            for (int r = 0; r < 4; ++r) {
                float lv = lrow[mt][r];
                lv += __shfl_xor(lv, 1);
                lv += __shfl_xor(lv, 2);
                lv += __shfl_xor(lv, 4);
                lv += __shfl_xor(lv, 8);
                if (l15 == 0)
                    atomicAdd(lsum + (size_t)bh*TT + qw0 + mt*16 + quad*4 + r, lv);
            }
        #pragma unroll
        for (int mt = 0; mt < 2; ++mt)
            #pragma unroll
            for (int nt = 0; nt < 4; ++nt)
                #pragma unroll
                for (int r = 0; r < 4; ++r) {
                    const int row = qw0 + mt*16 + quad*4 + r;
                    const int col = h*HDD + nt*16 + l15;
                    atomicAdd(yo + (size_t)(b*TT + row)*DDE + col, o[mt][nt][r]);
                }
    }
}

// ---------------------------------------------------------------------------
// MA: linear causal attention, uniform split-s (chunk=4 tiles).
// ---------------------------------------------------------------------------
__global__ __launch_bounds__(256) void attn_ma_mfma(
    const bf16_t* __restrict__ qab, const bf16_t* __restrict__ kcs,
    const bf16_t* __restrict__ etg, float* __restrict__ ma)
{
    int qt, ch;
    split_decode4((int)blockIdx.x, qt, ch);
    const int h = blockIdx.y, b = blockIdx.z;
    const int tid = threadIdx.x, wave = tid >> 6, lane = tid & 63;
    const int l15 = lane & 15, quad = lane >> 4;
    const int q0 = qt * 128;
    const int bh = b * NHH + h;

    __shared__ __align__(16) unsigned short Qs[128 * 64];
    __shared__ __align__(16) unsigned short Ks[64 * 64];
    __shared__ __align__(16) unsigned short Es[64 * 64];
    __shared__ __align__(16) unsigned short Pw[4][32 * 72];
    __shared__ float Rl[128];

    stage_tile<128>(qab + (size_t)(b*TT + q0)*DDE + h*HDD, DDE, Qs, wave, lane);
    __syncthreads();
    if (tid < 128) {
        float s = 0.f;
        #pragma unroll
        for (int c = 0; c < 8; ++c) {
            bf16x8 v = *(const bf16x8*)(Qs + tid*64 + c*8);
            #pragma unroll
            for (int u = 0; u < 8; ++u) s += (float)v[u];
        }
        Rl[tid] = s;
    }
    __syncthreads();

    bf16x8 qf[2][2];
    float Rr[2][4];
    #pragma unroll
    for (int mt = 0; mt < 2; ++mt) {
        #pragma unroll
        for (int kc = 0; kc < 2; ++kc)
            qf[mt][kc] = *(const bf16x8*)(Qs + (wave*32 + mt*16 + l15)*64
                                          + ((kc*4 + quad) ^ (l15 & 7))*8);
        #pragma unroll
        for (int r = 0; r < 4; ++r)
            Rr[mt][r] = 0.5f * Rl[wave*32 + mt*16 + quad*4 + r];
    }

    f32x4 o[2][4];
    #pragma unroll
    for (int mt = 0; mt < 2; ++mt)
        #pragma unroll
        for (int nt = 0; nt < 4; ++nt) o[mt][nt] = (f32x4)0.f;

    const int qw0 = q0 + wave * 32;
    const int kt0 = ch * 4;
    const int kt1 = min(kt0 + 4, 2*qt + 2);
    bool did = false;

    for (int kt = kt0; kt < kt1; ++kt) {
        const int s0 = kt * 64;
        __syncthreads();
        stage_tile<64>(kcs + (size_t)(b*TT + s0)*DDE + h*HDD, DDE, Ks, wave, lane);
        stage_tile<64>(etg + (size_t)(bh*64)*TT + s0, TT, Es, wave, lane);
        __syncthreads();
        if (s0 > qw0 + 31) continue;
        did = true;

        f32x4 sv[2][4];
        #pragma unroll
        for (int nt = 0; nt < 4; ++nt) {
            const unsigned short* kr = Ks + (nt*16 + l15)*64;
            bf16x8 kb0 = *(const bf16x8*)(kr + ((quad    ) ^ (l15 & 7))*8);
            bf16x8 kb1 = *(const bf16x8*)(kr + ((quad + 4) ^ (l15 & 7))*8);
            #pragma unroll
            for (int mt = 0; mt < 2; ++mt) {
                f32x4 z = (f32x4)0.f;
                z = MFMA(qf[mt][0], kb0, z);
                z = MFMA(qf[mt][1], kb1, z);
                sv[mt][nt] = z;
            }
        }
        const bool domask = (s0 + 63 > qw0);
        const bool m0 = (kt == 0);
        unsigned short* pw = Pw[wave];
        #pragma unroll
        for (int mt = 0; mt < 2; ++mt)
            #pragma unroll
            for (int r = 0; r < 4; ++r)
                #pragma unroll
                for (int nt = 0; nt < 4; ++nt) {
                    const int sg = s0 + nt*16 + l15;
                    float p = sv[mt][nt][r] + Rr[mt][r];
                    if (m0 && sg == 0) p = 0.f;
                    if (domask) {
                        const int qg = qw0 + mt*16 + quad*4 + r;
                        if (sg > qg) p = 0.f;
                    }
                    pw[(mt*16 + quad*4 + r)*72 + nt*16 + l15] = bf2us((bf16_t)p);
                }
        bf16x8 pa[2][2];
        #pragma unroll
        for (int mt = 0; mt < 2; ++mt)
            #pragma unroll
            for (int sc = 0; sc < 2; ++sc)
                pa[mt][sc] = *(const bf16x8*)(pw + (mt*16 + l15)*72 + sc*32 + quad*8);
        #pragma unroll
        for (int nt = 0; nt < 4; ++nt) {
            const unsigned short* er = Es + (nt*16 + l15)*64;
            bf16x8 eb0 = *(const bf16x8*)(er + ((quad    ) ^ (l15 & 7))*8);
            bf16x8 eb1 = *(const bf16x8*)(er + ((quad + 4) ^ (l15 & 7))*8);
            #pragma unroll
            for (int mt = 0; mt < 2; ++mt) {
                o[mt][nt] = MFMA(pa[mt][0], eb0, o[mt][nt]);
                o[mt][nt] = MFMA(pa[mt][1], eb1, o[mt][nt]);
            }
        }
    }

    if (did) {
        #pragma unroll
        for (int mt = 0; mt < 2; ++mt)
            #pragma unroll
            for (int nt = 0; nt < 4; ++nt)
                #pragma unroll
                for (int r = 0; r < 4; ++r) {
                    const int row = qw0 + mt*16 + quad*4 + r;
                    const int col = h*HDD + nt*16 + l15;
                    atomicAdd(ma + (size_t)(b*TT + row)*DDE + col, o[mt][nt][r]);
                }
    }
}

// ---------------------------------------------------------------------------
// ysumb = bf16( yarb + ma )
// ---------------------------------------------------------------------------
__global__ __launch_bounds__(256) void combine(
    const bf16_t* __restrict__ yarb, const float* __restrict__ ma,
    bf16_t* __restrict__ ysumb)
{
    const size_t e = ((size_t)blockIdx.x * 256 + threadIdx.x) * 4;
    bf16x4 a = *(const bf16x4*)(yarb + e);
    float4 m = *(const float4*)(ma + e);
    bf16x4 o;
    o[0] = (bf16_t)((float)a[0] + m.x);
    o[1] = (bf16_t)((float)a[1] + m.y);
    o[2] = (bf16_t)((float)a[2] + m.z);
    o[3] = (bf16_t)((float)a[3] + m.w);
    *(bf16x4*)(ysumb + e) = o;
}

// ---------------------------------------------------------------------------
extern "C" void kernel_launch(void* const* d_in, const int* in_sizes, int n_in,
                              void* d_out, int out_size, void* d_ws, size_t ws_size,
                              hipStream_t stream)
{
    const float* x      = (const float*)d_in[0];
    const float* w_attn = (const float*)d_in[1];
    const float* b_attn = (const float*)d_in[2];
    const float* w_k2   = (const float*)d_in[3];
    const float* b_k2   = (const float*)d_in[4];
    const float* w_proj = (const float*)d_in[5];
    const float* b_proj = (const float*)d_in[6];

    const size_t NX  = (size_t)BB*TT*DDE;
    const size_t NWA = (size_t)2*DDE*DDE;
    const size_t NW  = (size_t)DDE*DDE;
    const size_t NQK = (size_t)BB*TT*2*DDE;

    bf16_t* xb   = (bf16_t*)d_ws;
    bf16_t* wab  = xb   + NX;
    bf16_t* wkb  = wab  + NWA;
    bf16_t* wpb  = wkb  + NW;
    bf16_t* qkb  = wpb  + NW;      // aliased by maf (f32) after attn_ar
    bf16_t* qab  = qkb  + NQK;
    bf16_t* kcs  = qab  + NX;
    bf16_t* vtg  = kcs  + NX;      // aliased by etg after attn_ar
    float*  yo   = (float*)(vtg + NX);  // aliased by ysumb after norm_build
    bf16_t* yarb = (bf16_t*)(yo + NX);
    float*  lsum = (float*)wab;    // aliases wab after gemm_qkk2
    float*  maf  = (float*)qkb;
    bf16_t* etg  = vtg;
    bf16_t* ysumb= (bf16_t*)yo;

    hipMemsetAsync(yo, 0, NX * sizeof(float), stream);

    const size_t NCVT = NX + NWA + NW + NW;
    cvt_all<<<NCVT / 1024, 256, 0, stream>>>(x, w_attn, w_k2, w_proj, xb);

    transpose_head<<<dim3(TT/64, NHH, BB), 256, 0, stream>>>(xb, vtg);

    const int M = BB * TT;
    gemm_qkk2<<<dim3(24, M/128), 256, 0, stream>>>(xb, wab, wkb, b_attn, b_k2,
                                                    qkb, qab, kcs);
    hipMemsetAsync(lsum, 0, (size_t)BB*NHH*TT * sizeof(float), stream);

    attn_ar_mfma<<<dim3(72, NHH, BB), 256, 0, stream>>>(qkb, vtg, yo, lsum);
    norm_build_etg<<<dim3(TT/64, NHH, BB), 256, 0, stream>>>(yo, lsum, xb, yarb, etg);

    hipMemsetAsync(maf, 0, NX * sizeof(float), stream);
    attn_ma_mfma<<<dim3(72, NHH, BB), 256, 0, stream>>>(qab, kcs, etg, maf);

    combine<<<NX / 1024, 256, 0, stream>>>(yarb, maf, ysumb);
    gemm_proj<<<dim3(DDE/128, M/64), 256, 0, stream>>>(ysumb, wpb, b_proj,
                                                       (float*)d_out, M, DDE, DDE, 2.f);
}